// Round 1
// baseline (845.101 us; speedup 1.0000x reference)
//
#include <hip/hip_runtime.h>
#include <math.h>

#define H 16
#define B 4
#define S 1024
#define E 1024
#define DK 64

// ws layout (floats): Q[H*B*S*DK] | KT[H*B*DK*S] | V[H*B*S*DK] | CC[B*S*1024]
static constexpr size_t NQ = (size_t)H * B * S * DK;  // 4,194,304

// ---------------------------------------------------------------------------
// Kernel 1: fused QKV projection. Per head h:  emb[4096x1024] @ W[1024x64].
// which: 0=Q (direct), 1=K (scatter into reshaped-KT layout), 2=V (direct).
// 64x64 output tile per block, 4x4 per thread, K-step 32.
// ---------------------------------------------------------------------------
__global__ __launch_bounds__(256) void qkv_proj(
    const float* __restrict__ emb, const float* __restrict__ Wq,
    const float* __restrict__ Wk, const float* __restrict__ Wv,
    float* __restrict__ Q, float* __restrict__ KT, float* __restrict__ V)
{
    const int rt    = blockIdx.x;   // row tile: rows [rt*64, rt*64+64) of 4096
    const int which = blockIdx.y;   // 0=Q, 1=K, 2=V
    const int h     = blockIdx.z;
    const float* W = (which == 0 ? Wq : (which == 1 ? Wk : Wv)) + (size_t)h * E * DK;

    __shared__ float As[64][36];    // [row][k], KB=32, pad->36 (16B-aligned, bank-safe)
    __shared__ float Bs[32][64];    // [k][col]

    const int tid = threadIdx.x;
    const int ty = tid >> 4, tx = tid & 15;
    const int r0 = rt * 64;

    float acc[4][4] = {};

    for (int k0 = 0; k0 < E; k0 += 32) {
        // load A tile: 64x32 floats = 512 float4
        #pragma unroll
        for (int it = 0; it < 2; ++it) {
            int f = it * 256 + tid;
            int row = f >> 3, c4 = (f & 7) * 4;
            *(float4*)&As[row][c4] =
                *(const float4*)&emb[(size_t)(r0 + row) * E + k0 + c4];
        }
        // load B tile: 32x64 floats = 512 float4
        #pragma unroll
        for (int it = 0; it < 2; ++it) {
            int f = it * 256 + tid;
            int row = f >> 4, c4 = (f & 15) * 4;
            *(float4*)&Bs[row][c4] =
                *(const float4*)&W[(size_t)(k0 + row) * DK + c4];
        }
        __syncthreads();
        #pragma unroll 8
        for (int kk = 0; kk < 32; ++kk) {
            float4 bv = *(const float4*)&Bs[kk][tx * 4];
            float a[4];
            #pragma unroll
            for (int i = 0; i < 4; ++i) a[i] = As[ty * 4 + i][kk];
            #pragma unroll
            for (int i = 0; i < 4; ++i) {
                acc[i][0] += a[i] * bv.x;
                acc[i][1] += a[i] * bv.y;
                acc[i][2] += a[i] * bv.z;
                acc[i][3] += a[i] * bv.w;
            }
        }
        __syncthreads();
    }

    #pragma unroll
    for (int i = 0; i < 4; ++i) {
        int r = r0 + ty * 4 + i;
        int b = r >> 10, s = r & 1023;
        int d = tx * 4;
        float4 v = make_float4(acc[i][0], acc[i][1], acc[i][2], acc[i][3]);
        if (which == 0) {
            *(float4*)&Q[(((size_t)h * B + b) * S + s) * DK + d] = v;
        } else if (which == 2) {
            *(float4*)&V[(((size_t)h * B + b) * S + s) * DK + d] = v;
        } else {
            // reshaped-K: KT[hb][dd = s>>4][t = (s&15)*64 + dk], contiguous in dk
            *(float4*)&KT[(((size_t)h * B + b) * DK + (s >> 4)) * S + (s & 15) * 64 + d] = v;
        }
    }
}

// ---------------------------------------------------------------------------
// Kernel 2: causal flash attention per (h, b, 64-row query tile).
// scores[s,t] = ( Q[s,:]·KT[:,t] ) / 8, masked t>s, online softmax, @V.
// Output written directly into the scrambled concat (CC) layout.
// ---------------------------------------------------------------------------
__global__ __launch_bounds__(256) void attn(
    const float* __restrict__ Q, const float* __restrict__ KT,
    const float* __restrict__ V, float* __restrict__ CC)
{
    const int qt = blockIdx.x;          // query tile (s0 = qt*64)
    const int b  = blockIdx.y;
    const int h  = blockIdx.z;
    const size_t hb = (size_t)h * B + b;

    __shared__ float Qs[64][68];        // [s][d]
    __shared__ float U[64][68];         // union: K-tile [d][t], then P-tile [s][t]
    __shared__ float Vs[64][64];        // [t][dv]

    const int tid = threadIdx.x;
    const int ty = tid >> 4, tx = tid & 15;
    const int s0 = qt * 64;

    // load Q tile: 64x64 floats = 1024 float4
    #pragma unroll
    for (int it = 0; it < 4; ++it) {
        int f = it * 256 + tid;
        int row = f >> 4, c4 = (f & 15) * 4;
        *(float4*)&Qs[row][c4] = *(const float4*)&Q[(hb * S + s0 + row) * DK + c4];
    }

    float m[4], l[4] = {0.f, 0.f, 0.f, 0.f}, acc[4][4] = {};
    #pragma unroll
    for (int i = 0; i < 4; ++i) m[i] = -INFINITY;

    for (int t0 = 0; t0 <= s0; t0 += 64) {
        __syncthreads();  // previous iteration fully done with U / Vs
        // load K tile (into U) and V tile
        #pragma unroll
        for (int it = 0; it < 4; ++it) {
            int f = it * 256 + tid;
            int row = f >> 4, c4 = (f & 15) * 4;
            *(float4*)&U[row][c4]  = *(const float4*)&KT[(hb * DK + row) * S + t0 + c4];
            *(float4*)&Vs[row][c4] = *(const float4*)&V[(hb * S + t0 + row) * DK + c4];
        }
        __syncthreads();

        // scores: z[i][j] = sum_d Qs[s][d] * U[d][t]
        float z[4][4] = {};
        #pragma unroll 8
        for (int kk = 0; kk < 64; ++kk) {
            float4 bv = *(const float4*)&U[kk][tx * 4];
            float a[4];
            #pragma unroll
            for (int i = 0; i < 4; ++i) a[i] = Qs[ty * 4 + i][kk];
            #pragma unroll
            for (int i = 0; i < 4; ++i) {
                z[i][0] += a[i] * bv.x;
                z[i][1] += a[i] * bv.y;
                z[i][2] += a[i] * bv.z;
                z[i][3] += a[i] * bv.w;
            }
        }

        // scale + causal mask (only the diagonal tile has masked entries)
        const bool diag = (t0 == s0);
        #pragma unroll
        for (int i = 0; i < 4; ++i) {
            #pragma unroll
            for (int j = 0; j < 4; ++j) {
                z[i][j] *= 0.125f;
                if (diag && (t0 + tx * 4 + j > s0 + ty * 4 + i)) z[i][j] = -INFINITY;
            }
        }

        // online softmax update; row s lives in the 16 lanes sharing ty
        float p[4][4], mn[4], corr[4];
        #pragma unroll
        for (int i = 0; i < 4; ++i) {
            float mt = fmaxf(fmaxf(z[i][0], z[i][1]), fmaxf(z[i][2], z[i][3]));
            #pragma unroll
            for (int o = 1; o < 16; o <<= 1) mt = fmaxf(mt, __shfl_xor(mt, o));
            mn[i] = fmaxf(m[i], mt);
            corr[i] = __expf(m[i] - mn[i]);   // 0 when m was -inf
            float ps = 0.f;
            #pragma unroll
            for (int j = 0; j < 4; ++j) { p[i][j] = __expf(z[i][j] - mn[i]); ps += p[i][j]; }
            #pragma unroll
            for (int o = 1; o < 16; o <<= 1) ps += __shfl_xor(ps, o);
            l[i] = l[i] * corr[i] + ps;
            m[i] = mn[i];
            #pragma unroll
            for (int j = 0; j < 4; ++j) acc[i][j] *= corr[i];
        }

        __syncthreads();  // everyone done reading U as K-tile
        #pragma unroll
        for (int i = 0; i < 4; ++i)
            *(float4*)&U[ty * 4 + i][tx * 4] = make_float4(p[i][0], p[i][1], p[i][2], p[i][3]);
        __syncthreads();

        // acc += P @ V
        #pragma unroll 8
        for (int kk = 0; kk < 64; ++kk) {
            float4 vv = *(const float4*)&Vs[kk][tx * 4];
            float pa[4];
            #pragma unroll
            for (int i = 0; i < 4; ++i) pa[i] = U[ty * 4 + i][kk];
            #pragma unroll
            for (int i = 0; i < 4; ++i) {
                acc[i][0] += pa[i] * vv.x;
                acc[i][1] += pa[i] * vv.y;
                acc[i][2] += pa[i] * vv.z;
                acc[i][3] += pa[i] * vv.w;
            }
        }
    }

    // epilogue: write into scrambled concat layout
    #pragma unroll
    for (int i = 0; i < 4; ++i) {
        int sp = s0 + ty * 4 + i;
        float inv_l = 1.f / l[i];
        int bp  = h >> 2;
        int spp = (h & 3) * 256 + b * 64 + (sp >> 4);
        int c   = (sp & 15) * 64 + tx * 4;
        float4 v = make_float4(acc[i][0] * inv_l, acc[i][1] * inv_l,
                               acc[i][2] * inv_l, acc[i][3] * inv_l);
        *(float4*)&CC[((size_t)bp * S + spp) * 1024 + c] = v;
    }
}

// ---------------------------------------------------------------------------
// Kernel 3: output projection: CC[4096x1024] @ Wo[1024x1024] -> out
// ---------------------------------------------------------------------------
__global__ __launch_bounds__(256) void out_proj(
    const float* __restrict__ CC, const float* __restrict__ Wo,
    float* __restrict__ out)
{
    const int rt = blockIdx.x;   // 64-row tile of 4096
    const int ct = blockIdx.y;   // 64-col tile of 1024

    __shared__ float As[64][36];
    __shared__ float Bs[32][64];

    const int tid = threadIdx.x;
    const int ty = tid >> 4, tx = tid & 15;
    const int r0 = rt * 64, c0 = ct * 64;

    float acc[4][4] = {};

    for (int k0 = 0; k0 < 1024; k0 += 32) {
        #pragma unroll
        for (int it = 0; it < 2; ++it) {
            int f = it * 256 + tid;
            int row = f >> 3, c4 = (f & 7) * 4;
            *(float4*)&As[row][c4] =
                *(const float4*)&CC[(size_t)(r0 + row) * 1024 + k0 + c4];
        }
        #pragma unroll
        for (int it = 0; it < 2; ++it) {
            int f = it * 256 + tid;
            int row = f >> 4, c4 = (f & 15) * 4;
            *(float4*)&Bs[row][c4] =
                *(const float4*)&Wo[(size_t)(k0 + row) * 1024 + c0 + c4];
        }
        __syncthreads();
        #pragma unroll 8
        for (int kk = 0; kk < 32; ++kk) {
            float4 bv = *(const float4*)&Bs[kk][tx * 4];
            float a[4];
            #pragma unroll
            for (int i = 0; i < 4; ++i) a[i] = As[ty * 4 + i][kk];
            #pragma unroll
            for (int i = 0; i < 4; ++i) {
                acc[i][0] += a[i] * bv.x;
                acc[i][1] += a[i] * bv.y;
                acc[i][2] += a[i] * bv.z;
                acc[i][3] += a[i] * bv.w;
            }
        }
        __syncthreads();
    }

    #pragma unroll
    for (int i = 0; i < 4; ++i) {
        int r = r0 + ty * 4 + i;
        *(float4*)&out[(size_t)r * 1024 + c0 + tx * 4] =
            make_float4(acc[i][0], acc[i][1], acc[i][2], acc[i][3]);
    }
}

extern "C" void kernel_launch(void* const* d_in, const int* in_sizes, int n_in,
                              void* d_out, int out_size, void* d_ws, size_t ws_size,
                              hipStream_t stream)
{
    const float* emb = (const float*)d_in[0];
    const float* Wq  = (const float*)d_in[1];
    const float* Wk  = (const float*)d_in[2];
    const float* Wv  = (const float*)d_in[3];
    const float* Wo  = (const float*)d_in[4];
    float* out = (float*)d_out;

    float* Q  = (float*)d_ws;
    float* KT = Q + NQ;
    float* V  = KT + NQ;
    float* CC = V + NQ;

    qkv_proj<<<dim3(64, 3, H), 256, 0, stream>>>(emb, Wq, Wk, Wv, Q, KT, V);
    attn<<<dim3(S / 64, B, H), 256, 0, stream>>>(Q, KT, V, CC);
    out_proj<<<dim3(64, 16), 256, 0, stream>>>(CC, Wo, out);
}

// Round 3
// 261.983 us; speedup vs baseline: 3.2258x; 3.2258x over previous
//
#include <hip/hip_runtime.h>
#include <math.h>

#define H 16
#define B 4
#define S 1024
#define E 1024
#define DK 64

typedef _Float16 f16x8 __attribute__((ext_vector_type(8)));
typedef _Float16 f16x4 __attribute__((ext_vector_type(4)));
typedef float    f32x4 __attribute__((ext_vector_type(4)));

// XOR-swizzle for [r][64 f16] tiles (128B row stride): conflict-free b128.
__device__ __forceinline__ int swzb(int row, int colByte) {
    return row * 128 + (colByte ^ ((row & 7) << 4));
}
// XOR-swizzle for [r][32 f16] tiles (64B row stride). slot = (r&3)^((r>>2)&3)
// spreads 16-row b128 frag reads across 8 slots -> 2-way (free).
__device__ __forceinline__ int swz32(int row, int colByte) {
    int slot = ((row & 3) ^ ((row >> 2) & 3)) << 4;
    return row * 64 + (colByte ^ slot);
}

// split 8 consecutive f32 into hi/lo f16 (double-f16 representation)
__device__ __forceinline__ void split8(const float* __restrict__ p,
                                       f16x8& hi, f16x8& lo) {
    float4 a = *(const float4*)p;
    float4 b = *(const float4*)(p + 4);
    float x[8] = {a.x, a.y, a.z, a.w, b.x, b.y, b.z, b.w};
    #pragma unroll
    for (int j = 0; j < 8; ++j) {
        _Float16 h = (_Float16)x[j];
        hi[j] = h;
        lo[j] = (_Float16)(x[j] - (float)h);
    }
}

// ---------------------------------------------------------------------------
// Wq/Wk/Wv [h][e][d] f32 -> WTh [n][e] (n = which*1024 + h*64 + d), hi part;
// WTl same for n < 2048 (Q,K only). grid: (16 e-tiles, 48 chunks)
// ---------------------------------------------------------------------------
__global__ __launch_bounds__(256) void cvt_w(const float* __restrict__ Wq,
                                             const float* __restrict__ Wk,
                                             const float* __restrict__ Wv,
                                             _Float16* __restrict__ WTh,
                                             _Float16* __restrict__ WTl) {
    int et = blockIdx.x, chunk = blockIdx.y;
    const float* W = (chunk < 16 ? Wq : chunk < 32 ? Wk : Wv)
                     + (size_t)(chunk & 15) * E * DK;
    __shared__ _Float16 Th[64 * 64];
    __shared__ _Float16 Tl[64 * 64];
    int tid = threadIdx.x;
    #pragma unroll
    for (int rr = 0; rr < 4; ++rr) {
        int u = rr * 256 + tid;
        int ei = u >> 4, f4 = u & 15;
        float4 v = *(const float4*)&W[(size_t)(et * 64 + ei) * 64 + f4 * 4];
        float x[4] = {v.x, v.y, v.z, v.w};
        f16x4 h, l;
        #pragma unroll
        for (int j = 0; j < 4; ++j) {
            _Float16 hh = (_Float16)x[j];
            h[j] = hh;
            l[j] = (_Float16)(x[j] - (float)hh);
        }
        *(f16x4*)((char*)Th + swzb(ei, f4 * 8)) = h;
        *(f16x4*)((char*)Tl + swzb(ei, f4 * 8)) = l;
    }
    __syncthreads();
    #pragma unroll
    for (int rr = 0; rr < 2; ++rr) {
        int u = rr * 256 + tid;
        int d = u >> 3, e8 = u & 7;
        f16x8 oh, ol;
        #pragma unroll
        for (int j = 0; j < 8; ++j) {
            int ei = e8 * 8 + j;
            oh[j] = *(_Float16*)((char*)Th + swzb(ei, d * 2));
            ol[j] = *(_Float16*)((char*)Tl + swzb(ei, d * 2));
        }
        size_t idx = (size_t)(chunk * 64 + d) * 1024 + et * 64 + e8 * 8;
        *(f16x8*)&WTh[idx] = oh;
        if (chunk < 32) *(f16x8*)&WTl[idx] = ol;
    }
}

// ---------------------------------------------------------------------------
// Wo [k][n] f32 -> WoT f16 [n][k].  grid: (16 k-tiles, 16 n-tiles)
// ---------------------------------------------------------------------------
__global__ __launch_bounds__(256) void cvt_wo(const float* __restrict__ Wo,
                                              _Float16* __restrict__ WoT) {
    int kt = blockIdx.x, nt = blockIdx.y;
    __shared__ _Float16 T[64 * 64];
    int tid = threadIdx.x;
    #pragma unroll
    for (int rr = 0; rr < 4; ++rr) {
        int u = rr * 256 + tid;
        int ki = u >> 4, f4 = u & 15;
        float4 v = *(const float4*)&Wo[(size_t)(kt * 64 + ki) * 1024 + nt * 64 + f4 * 4];
        f16x4 o = { (_Float16)v.x, (_Float16)v.y, (_Float16)v.z, (_Float16)v.w };
        *(f16x4*)((char*)T + swzb(ki, f4 * 8)) = o;
    }
    __syncthreads();
    #pragma unroll
    for (int rr = 0; rr < 2; ++rr) {
        int u = rr * 256 + tid;
        int nl = u >> 3, k8 = u & 7;
        f16x8 o;
        #pragma unroll
        for (int j = 0; j < 8; ++j) {
            int ki = k8 * 8 + j;
            o[j] = *(_Float16*)((char*)T + swzb(ki, nl * 2));
        }
        *(f16x8*)&WoT[(size_t)(nt * 64 + nl) * 1024 + kt * 64 + k8 * 8] = o;
    }
}

// ---------------------------------------------------------------------------
// Fused QKV projection GEMM, double-f16 precision for Q,K columns.
//   A = emb f32 [4096][1024] (split hi/lo during staging)
//   BT = WTh [3072][1024] + WTl [2048][1024]
// 128x128 tile, BK=32, 2x2 waves of 64x64 (4x4 frags). Q,K tiles: 3-term MFMA.
// Epilogue: Q -> QbH/QbL [hb][s][dk]; K -> kkTH/kkTL [hb][d][t] (reshaped-K,
// coalesced); V -> V2 [hb][dv][t] (pre-transposed), single precision.
// ---------------------------------------------------------------------------
__global__ __launch_bounds__(256) void gemm_qkv(
    const float* __restrict__ A, const _Float16* __restrict__ BTh,
    const _Float16* __restrict__ BTl,
    _Float16* __restrict__ QbH, _Float16* __restrict__ QbL,
    _Float16* __restrict__ kkTH, _Float16* __restrict__ kkTL,
    _Float16* __restrict__ V2) {
    __shared__ _Float16 AsH[128 * 32], AsL[128 * 32];
    __shared__ _Float16 BsH[128 * 32], BsL[128 * 32];
    const int NT = 24, cpx = 96;             // 768 wgs, 768%8==0 -> bijective
    int wg = ((int)blockIdx.x & 7) * cpx + ((int)blockIdx.x >> 3);
    int mt = wg / NT, nt = wg % NT;
    const bool qk = (nt < 16);
    int r0 = mt * 128, c0 = nt * 128;
    int tid = threadIdx.x, lane = tid & 63, w = tid >> 6;
    int wr = w >> 1, wc = w & 1;
    int l15 = lane & 15, l4 = lane >> 4;

    f16x8 raH[2], raL[2], rbH[2], rbL[2];
    f32x4 zero = {0.f, 0.f, 0.f, 0.f};
    f32x4 acc[4][4];
    #pragma unroll
    for (int i = 0; i < 4; ++i)
        #pragma unroll
        for (int j = 0; j < 4; ++j) acc[i][j] = zero;

    // prologue loads (k0 = 0)
    #pragma unroll
    for (int rr = 0; rr < 2; ++rr) {
        int u = rr * 256 + tid, row = u >> 2, c8 = u & 3;
        split8(&A[(size_t)(r0 + row) * 1024 + c8 * 8], raH[rr], raL[rr]);
        rbH[rr] = *(const f16x8*)&BTh[(size_t)(c0 + row) * 1024 + c8 * 8];
        if (qk) rbL[rr] = *(const f16x8*)&BTl[(size_t)(c0 + row) * 1024 + c8 * 8];
    }

    for (int kt = 0; kt < 32; ++kt) {
        __syncthreads();
        #pragma unroll
        for (int rr = 0; rr < 2; ++rr) {
            int u = rr * 256 + tid, row = u >> 2, cb = (u & 3) * 16;
            int off = swz32(row, cb);
            *(f16x8*)((char*)AsH + off) = raH[rr];
            *(f16x8*)((char*)AsL + off) = raL[rr];
            *(f16x8*)((char*)BsH + off) = rbH[rr];
            if (qk) *(f16x8*)((char*)BsL + off) = rbL[rr];
        }
        if (kt < 31) {                       // issue-early next-tile loads
            int k0 = (kt + 1) * 32;
            #pragma unroll
            for (int rr = 0; rr < 2; ++rr) {
                int u = rr * 256 + tid, row = u >> 2, c8 = u & 3;
                split8(&A[(size_t)(r0 + row) * 1024 + k0 + c8 * 8], raH[rr], raL[rr]);
                rbH[rr] = *(const f16x8*)&BTh[(size_t)(c0 + row) * 1024 + k0 + c8 * 8];
                if (qk) rbL[rr] = *(const f16x8*)&BTl[(size_t)(c0 + row) * 1024 + k0 + c8 * 8];
            }
        }
        __syncthreads();
        int kb = l4 * 16;                    // k-slice byte offset (l4*8 f16)
        f16x8 afH[4], afL[4], bfH[4], bfL[4];
        #pragma unroll
        for (int f = 0; f < 4; ++f) {
            int arow = wr * 64 + f * 16 + l15;
            int brow = wc * 64 + f * 16 + l15;
            afH[f] = *(const f16x8*)((char*)AsH + swz32(arow, kb));
            bfH[f] = *(const f16x8*)((char*)BsH + swz32(brow, kb));
            if (qk) {
                afL[f] = *(const f16x8*)((char*)AsL + swz32(arow, kb));
                bfL[f] = *(const f16x8*)((char*)BsL + swz32(brow, kb));
            }
        }
        #pragma unroll
        for (int i = 0; i < 4; ++i)
            #pragma unroll
            for (int j = 0; j < 4; ++j) {
                acc[i][j] = __builtin_amdgcn_mfma_f32_16x16x32_f16(
                    afH[i], bfH[j], acc[i][j], 0, 0, 0);
                if (qk) {
                    acc[i][j] = __builtin_amdgcn_mfma_f32_16x16x32_f16(
                        afH[i], bfL[j], acc[i][j], 0, 0, 0);
                    acc[i][j] = __builtin_amdgcn_mfma_f32_16x16x32_f16(
                        afL[i], bfH[j], acc[i][j], 0, 0, 0);
                }
            }
    }

    #pragma unroll
    for (int i = 0; i < 4; ++i) {
        int grow0 = r0 + wr * 64 + i * 16 + l4 * 4;
        #pragma unroll
        for (int j = 0; j < 4; ++j) {
            int gcol = c0 + wc * 64 + j * 16 + l15;
            if (gcol < 1024) {                       // ---- Q (split) ----
                int hh = gcol >> 6, dk = gcol & 63;
                #pragma unroll
                for (int r = 0; r < 4; ++r) {
                    int grow = grow0 + r;
                    int bb = grow >> 10, s = grow & 1023;
                    float v = acc[i][j][r];
                    _Float16 h = (_Float16)v;
                    size_t idx = (((size_t)hh * 4 + bb) * 1024 + s) * 64 + dk;
                    QbH[idx] = h;
                    QbL[idx] = (_Float16)(v - (float)h);
                }
            } else if (gcol < 2048) {                // ---- K (split, reshaped) ----
                int hh = (gcol >> 6) & 15, dk = gcol & 63;
                #pragma unroll
                for (int r = 0; r < 4; ++r) {
                    int grow = grow0 + r;
                    int bb = grow >> 10, s = grow & 1023;
                    float v = acc[i][j][r];
                    _Float16 h = (_Float16)v;
                    // kkT[d = s>>4][t = (s&15)*64 + dk]
                    size_t idx = (((size_t)hh * 4 + bb) * 64 + (s >> 4)) * 1024
                                 + (s & 15) * 64 + dk;
                    kkTH[idx] = h;
                    kkTL[idx] = (_Float16)(v - (float)h);
                }
            } else {                                 // ---- V (pre-transposed) ----
                int hh = (gcol >> 6) & 15, dv = gcol & 63;
                int bb = grow0 >> 10, s = grow0 & 1023;
                f16x4 o = { (_Float16)acc[i][j][0], (_Float16)acc[i][j][1],
                            (_Float16)acc[i][j][2], (_Float16)acc[i][j][3] };
                *(f16x4*)&V2[(((size_t)hh * 4 + bb) * 64 + dv) * 1024 + s] = o;
            }
        }
    }
}

// ---------------------------------------------------------------------------
// kkT [hb][64 d][1024 t] -> K2 [hb][1024 t][64 d], modes: 0=hi, 1=lo.
// grid: (16 t-tiles, 64 hb, 2 modes)
// ---------------------------------------------------------------------------
__global__ __launch_bounds__(256) void trans_k(const _Float16* __restrict__ kkTH,
                                               const _Float16* __restrict__ kkTL,
                                               _Float16* __restrict__ K2H,
                                               _Float16* __restrict__ K2L) {
    int tt = blockIdx.x;
    size_t hb = blockIdx.y;
    int mode = blockIdx.z;
    const _Float16* src = mode ? kkTL : kkTH;
    _Float16* dst = mode ? K2L : K2H;
    __shared__ _Float16 T[64 * 64];
    int tid = threadIdx.x;
    #pragma unroll
    for (int rr = 0; rr < 2; ++rr) {
        int u = rr * 256 + tid;
        int d = u >> 3, c8 = u & 7;
        f16x8 v = *(const f16x8*)&src[(hb * 64 + d) * 1024 + tt * 64 + c8 * 8];
        *(f16x8*)((char*)T + swzb(d, c8 * 16)) = v;
    }
    __syncthreads();
    #pragma unroll
    for (int rr = 0; rr < 2; ++rr) {
        int u = rr * 256 + tid;
        int ti = u >> 3, d8 = u & 7;
        f16x8 o;
        #pragma unroll
        for (int j = 0; j < 8; ++j)
            o[j] = *(_Float16*)((char*)T + swzb(d8 * 8 + j, ti * 2));
        *(f16x8*)&dst[(hb * 1024 + tt * 64 + ti) * 64 + d8 * 8] = o;
    }
}

// ---------------------------------------------------------------------------
// Flash attention, double-f16 QK^T (3 MFMA terms), per (qt, b, h).
// Each wave owns 16 q-rows (lane l15 -> q-row); lane-local online softmax.
// PV via mfma(V2_tile, P^T). Output -> scrambled concat CC, f16.
// ---------------------------------------------------------------------------
__global__ __launch_bounds__(256) void attn(
    const _Float16* __restrict__ QbH, const _Float16* __restrict__ QbL,
    const _Float16* __restrict__ K2H, const _Float16* __restrict__ K2L,
    const _Float16* __restrict__ V2, _Float16* __restrict__ CC) {
    int qt = blockIdx.x, b = blockIdx.y, h = blockIdx.z;
    size_t hb = (size_t)h * 4 + b;
    __shared__ _Float16 QsH[64 * 64], QsL[64 * 64];
    __shared__ _Float16 KsH[64 * 64], KsL[64 * 64];
    __shared__ _Float16 Vs[64 * 64], Ps[64 * 64];
    int tid = threadIdx.x, lane = tid & 63, w = tid >> 6;
    int l15 = lane & 15, l4 = lane >> 4;
    int s0 = qt * 64;

    #pragma unroll
    for (int rr = 0; rr < 2; ++rr) {
        int u = rr * 256 + tid, row = u >> 3, c8 = u & 7;
        size_t gi = (hb * 1024 + s0 + row) * 64 + c8 * 8;
        int off = swzb(row, c8 * 16);
        *(f16x8*)((char*)QsH + off) = *(const f16x8*)&QbH[gi];
        *(f16x8*)((char*)QsL + off) = *(const f16x8*)&QbL[gi];
    }
    __syncthreads();
    int srow = w * 16 + l15;
    f16x8 qfH[2], qfL[2];
    #pragma unroll
    for (int ks = 0; ks < 2; ++ks) {
        int kb = (ks * 32 + l4 * 8) * 2;
        qfH[ks] = *(const f16x8*)((char*)QsH + swzb(srow, kb));
        qfL[ks] = *(const f16x8*)((char*)QsL + swzb(srow, kb));
    }

    float m = -__builtin_inff(), lsum = 0.f;
    f32x4 zero = {0.f, 0.f, 0.f, 0.f};
    f32x4 acc2[4] = {zero, zero, zero, zero};
    int sg = s0 + srow;
    int ntile = qt + 1;

    for (int tt = 0; tt < ntile; ++tt) {
        int t0 = tt * 64;
        __syncthreads();
        #pragma unroll
        for (int rr = 0; rr < 2; ++rr) {
            int u = rr * 256 + tid, row = u >> 3, c8 = u & 7;
            int off = swzb(row, c8 * 16);
            size_t ki = (hb * 1024 + t0 + row) * 64 + c8 * 8;
            *(f16x8*)((char*)KsH + off) = *(const f16x8*)&K2H[ki];
            *(f16x8*)((char*)KsL + off) = *(const f16x8*)&K2L[ki];
            *(f16x8*)((char*)Vs + off) =
                *(const f16x8*)&V2[(hb * 64 + row) * 1024 + t0 + c8 * 8];
        }
        __syncthreads();

        f32x4 z[4] = {zero, zero, zero, zero};
        #pragma unroll
        for (int ks = 0; ks < 2; ++ks) {
            int kb = (ks * 32 + l4 * 8) * 2;
            #pragma unroll
            for (int f = 0; f < 4; ++f) {
                int trow = f * 16 + l15;
                f16x8 akH = *(const f16x8*)((char*)KsH + swzb(trow, kb));
                f16x8 akL = *(const f16x8*)((char*)KsL + swzb(trow, kb));
                z[f] = __builtin_amdgcn_mfma_f32_16x16x32_f16(akH, qfH[ks], z[f], 0, 0, 0);
                z[f] = __builtin_amdgcn_mfma_f32_16x16x32_f16(akH, qfL[ks], z[f], 0, 0, 0);
                z[f] = __builtin_amdgcn_mfma_f32_16x16x32_f16(akL, qfH[ks], z[f], 0, 0, 0);
            }
        }
        // scale + causal mask + lane-local row max
        float mt = -__builtin_inff();
        #pragma unroll
        for (int f = 0; f < 4; ++f)
            #pragma unroll
            for (int r = 0; r < 4; ++r) {
                int tg = t0 + f * 16 + l4 * 4 + r;
                float val = z[f][r] * 0.125f;
                val = (tg > sg) ? -__builtin_inff() : val;
                z[f][r] = val;
                mt = fmaxf(mt, val);
            }
        mt = fmaxf(mt, __shfl_xor(mt, 16));
        mt = fmaxf(mt, __shfl_xor(mt, 32));
        float mn = fmaxf(m, mt);
        float corr = __expf(m - mn);
        float ps = 0.f;
        #pragma unroll
        for (int f = 0; f < 4; ++f)
            #pragma unroll
            for (int r = 0; r < 4; ++r) {
                float p = __expf(z[f][r] - mn);
                z[f][r] = p;
                ps += p;
            }
        ps += __shfl_xor(ps, 16);
        ps += __shfl_xor(ps, 32);
        lsum = lsum * corr + ps;
        m = mn;
        #pragma unroll
        for (int f = 0; f < 4; ++f) acc2[f] *= corr;

        // P^T -> Ps[s][t] (wave-private rows, no barrier needed)
        #pragma unroll
        for (int f = 0; f < 4; ++f) {
            f16x4 pk = { (_Float16)z[f][0], (_Float16)z[f][1],
                         (_Float16)z[f][2], (_Float16)z[f][3] };
            *(f16x4*)((char*)Ps + swzb(srow, (f * 16 + l4 * 4) * 2)) = pk;
        }
        #pragma unroll
        for (int ks = 0; ks < 2; ++ks) {
            int kb = (ks * 32 + l4 * 8) * 2;
            f16x8 bp = *(const f16x8*)((char*)Ps + swzb(srow, kb));
            #pragma unroll
            for (int f = 0; f < 4; ++f) {
                int dvrow = f * 16 + l15;
                f16x8 av = *(const f16x8*)((char*)Vs + swzb(dvrow, kb));
                acc2[f] = __builtin_amdgcn_mfma_f32_16x16x32_f16(av, bp, acc2[f], 0, 0, 0);
            }
        }
    }

    float inv = 1.f / lsum;
    int sp = s0 + srow;
    int bprow = h >> 2;
    int spp = (h & 3) * 256 + b * 64 + (sp >> 4);
    int cb = (sp & 15) * 64;
    #pragma unroll
    for (int f = 0; f < 4; ++f) {
        int dv = f * 16 + l4 * 4;
        f16x4 o = { (_Float16)(acc2[f][0] * inv), (_Float16)(acc2[f][1] * inv),
                    (_Float16)(acc2[f][2] * inv), (_Float16)(acc2[f][3] * inv) };
        *(f16x4*)&CC[((size_t)bprow * 1024 + spp) * 1024 + cb + dv] = o;
    }
}

// ---------------------------------------------------------------------------
// Output projection: CC[4096][1024] f16 @ WoT[1024][1024]^T -> out f32
// ---------------------------------------------------------------------------
__global__ __launch_bounds__(256) void gemm_out(
    const _Float16* __restrict__ A, const _Float16* __restrict__ BT,
    float* __restrict__ out) {
    __shared__ _Float16 As[128 * 64];
    __shared__ _Float16 Bs[128 * 64];
    const int NT = 8, cpx = 32;              // 256 wgs
    int wg = ((int)blockIdx.x & 7) * cpx + ((int)blockIdx.x >> 3);
    int mt = wg / NT, nt = wg % NT;
    int r0 = mt * 128, c0 = nt * 128;
    int tid = threadIdx.x, lane = tid & 63, w = tid >> 6;
    int wr = w >> 1, wc = w & 1;
    int l15 = lane & 15, l4 = lane >> 4;

    f16x8 ra[4], rb[4];
    f32x4 zero = {0.f, 0.f, 0.f, 0.f};
    f32x4 acc[4][4];
    #pragma unroll
    for (int i = 0; i < 4; ++i)
        #pragma unroll
        for (int j = 0; j < 4; ++j) acc[i][j] = zero;

    #pragma unroll
    for (int rr = 0; rr < 4; ++rr) {
        int u = rr * 256 + tid, row = u >> 3, c8 = u & 7;
        ra[rr] = *(const f16x8*)&A [(size_t)(r0 + row) * 1024 + c8 * 8];
        rb[rr] = *(const f16x8*)&BT[(size_t)(c0 + row) * 1024 + c8 * 8];
    }

    for (int kt = 0; kt < 16; ++kt) {
        __syncthreads();
        #pragma unroll
        for (int rr = 0; rr < 4; ++rr) {
            int u = rr * 256 + tid, row = u >> 3, c8 = u & 7;
            int off = swzb(row, c8 * 16);
            *(f16x8*)((char*)As + off) = ra[rr];
            *(f16x8*)((char*)Bs + off) = rb[rr];
        }
        if (kt < 15) {
            int k0 = (kt + 1) * 64;
            #pragma unroll
            for (int rr = 0; rr < 4; ++rr) {
                int u = rr * 256 + tid, row = u >> 3, c8 = u & 7;
                ra[rr] = *(const f16x8*)&A [(size_t)(r0 + row) * 1024 + k0 + c8 * 8];
                rb[rr] = *(const f16x8*)&BT[(size_t)(c0 + row) * 1024 + k0 + c8 * 8];
            }
        }
        __syncthreads();
        #pragma unroll
        for (int ks = 0; ks < 2; ++ks) {
            int kb = (ks * 32 + l4 * 8) * 2;
            f16x8 af[4], bf[4];
            #pragma unroll
            for (int f = 0; f < 4; ++f) {
                int arow = wr * 64 + f * 16 + l15;
                int brow = wc * 64 + f * 16 + l15;
                af[f] = *(const f16x8*)((char*)As + swzb(arow, kb));
                bf[f] = *(const f16x8*)((char*)Bs + swzb(brow, kb));
            }
            #pragma unroll
            for (int i = 0; i < 4; ++i)
                #pragma unroll
                for (int j = 0; j < 4; ++j)
                    acc[i][j] = __builtin_amdgcn_mfma_f32_16x16x32_f16(
                        af[i], bf[j], acc[i][j], 0, 0, 0);
        }
    }

    #pragma unroll
    for (int i = 0; i < 4; ++i) {
        int grow0 = r0 + wr * 64 + i * 16 + l4 * 4;
        #pragma unroll
        for (int j = 0; j < 4; ++j) {
            int gcol = c0 + wc * 64 + j * 16 + l15;
            #pragma unroll
            for (int r = 0; r < 4; ++r)
                out[(size_t)(grow0 + r) * 1024 + gcol] = acc[i][j][r];
        }
    }
}

// ---------------------------------------------------------------------------
extern "C" void kernel_launch(void* const* d_in, const int* in_sizes, int n_in,
                              void* d_out, int out_size, void* d_ws, size_t ws_size,
                              hipStream_t stream) {
    const float* emb = (const float*)d_in[0];
    const float* Wq  = (const float*)d_in[1];
    const float* Wk  = (const float*)d_in[2];
    const float* Wv  = (const float*)d_in[3];
    const float* Wo  = (const float*)d_in[4];
    float* out = (float*)d_out;

    // ws: 60 MB total (<= 64 MB proven-safe footprint)
    _Float16* WTh = (_Float16*)d_ws;           // 3,145,728
    _Float16* WTl = WTh + 3145728;             // 2,097,152
    _Float16* WoT = WTl + 2097152;             // 1,048,576
    _Float16* QbH = WoT + 1048576;             // 4,194,304
    _Float16* QbL = QbH + 4194304;
    _Float16* K2H = QbL + 4194304;
    _Float16* K2L = K2H + 4194304;
    _Float16* V2  = K2L + 4194304;
    _Float16* CC  = V2  + 4194304;
    // kkT hi/lo parked in d_out (16 MB), dead before gemm_out writes it
    _Float16* kkTH = (_Float16*)d_out;
    _Float16* kkTL = kkTH + 4194304;

    cvt_w   <<<dim3(16, 48), 256, 0, stream>>>(Wq, Wk, Wv, WTh, WTl);
    cvt_wo  <<<dim3(16, 16), 256, 0, stream>>>(Wo, WoT);
    gemm_qkv<<<768, 256, 0, stream>>>(emb, WTh, WTl, QbH, QbL, kkTH, kkTL, V2);
    trans_k <<<dim3(16, 64, 2), 256, 0, stream>>>(kkTH, kkTL, K2H, K2L);
    attn    <<<dim3(16, 4, 16), 256, 0, stream>>>(QbH, QbL, K2H, K2L, V2, CC);
    gemm_out<<<256, 256, 0, stream>>>(CC, WoT, out);
}

// Round 5
// 253.270 us; speedup vs baseline: 3.3368x; 1.0344x over previous
//
#include <hip/hip_runtime.h>
#include <math.h>

#define H 16
#define B 4
#define S 1024
#define E 1024
#define DK 64

typedef _Float16 f16x8 __attribute__((ext_vector_type(8)));
typedef _Float16 f16x4 __attribute__((ext_vector_type(4)));
typedef float    f32x4 __attribute__((ext_vector_type(4)));

// XOR-swizzle for [r][64 f16] tiles (128B row stride) — used by reg-staged
// kernels (attn, cvt) only. gload_lds kernels use linear LDS (rule #21).
__device__ __forceinline__ int swzb(int row, int colByte) {
    return row * 128 + (colByte ^ ((row & 7) << 4));
}

// ---------------------------------------------------------------------------
// emb f32 -> embH + embL f16 (double-f16 split). 8 elems/thread.
// ---------------------------------------------------------------------------
__global__ __launch_bounds__(256) void cvt_split_emb(const float* __restrict__ in,
                                                     _Float16* __restrict__ outH,
                                                     _Float16* __restrict__ outL) {
    int i = (blockIdx.x * 256 + threadIdx.x) * 8;
    float4 a = *(const float4*)&in[i];
    float4 b = *(const float4*)&in[i + 4];
    float x[8] = {a.x, a.y, a.z, a.w, b.x, b.y, b.z, b.w};
    f16x8 h, l;
    #pragma unroll
    for (int j = 0; j < 8; ++j) {
        _Float16 hh = (_Float16)x[j];
        h[j] = hh;
        l[j] = (_Float16)(x[j] - (float)hh);
    }
    *(f16x8*)&outH[i] = h;
    *(f16x8*)&outL[i] = l;
}

// ---------------------------------------------------------------------------
// Merged weight conversion.
// y<48: Wq/Wk/Wv [h][e][d] -> WTh [n][e] (+WTl for n<2048), transposed+split.
// y>=48: Wo [k][n] -> WoT [n][k], f16.
// grid (16, 64)
// ---------------------------------------------------------------------------
__global__ __launch_bounds__(256) void cvt_weights(
    const float* __restrict__ Wq, const float* __restrict__ Wk,
    const float* __restrict__ Wv, const float* __restrict__ Wo,
    _Float16* __restrict__ WTh, _Float16* __restrict__ WTl,
    _Float16* __restrict__ WoT) {
    __shared__ _Float16 Th[64 * 64];
    __shared__ _Float16 Tl[64 * 64];
    int tid = threadIdx.x;
    if (blockIdx.y < 48) {
        int et = blockIdx.x, chunk = blockIdx.y;
        const float* W = (chunk < 16 ? Wq : chunk < 32 ? Wk : Wv)
                         + (size_t)(chunk & 15) * E * DK;
        #pragma unroll
        for (int rr = 0; rr < 4; ++rr) {
            int u = rr * 256 + tid;
            int ei = u >> 4, f4 = u & 15;
            float4 v = *(const float4*)&W[(size_t)(et * 64 + ei) * 64 + f4 * 4];
            float x[4] = {v.x, v.y, v.z, v.w};
            f16x4 h, l;
            #pragma unroll
            for (int j = 0; j < 4; ++j) {
                _Float16 hh = (_Float16)x[j];
                h[j] = hh;
                l[j] = (_Float16)(x[j] - (float)hh);
            }
            *(f16x4*)((char*)Th + swzb(ei, f4 * 8)) = h;
            *(f16x4*)((char*)Tl + swzb(ei, f4 * 8)) = l;
        }
        __syncthreads();
        #pragma unroll
        for (int rr = 0; rr < 2; ++rr) {
            int u = rr * 256 + tid;
            int d = u >> 3, e8 = u & 7;
            f16x8 oh, ol;
            #pragma unroll
            for (int j = 0; j < 8; ++j) {
                int ei = e8 * 8 + j;
                oh[j] = *(_Float16*)((char*)Th + swzb(ei, d * 2));
                ol[j] = *(_Float16*)((char*)Tl + swzb(ei, d * 2));
            }
            size_t idx = (size_t)(chunk * 64 + d) * 1024 + et * 64 + e8 * 8;
            *(f16x8*)&WTh[idx] = oh;
            if (chunk < 32) *(f16x8*)&WTl[idx] = ol;
        }
    } else {
        int kt = blockIdx.x, nt = blockIdx.y - 48;
        #pragma unroll
        for (int rr = 0; rr < 4; ++rr) {
            int u = rr * 256 + tid;
            int ki = u >> 4, f4 = u & 15;
            float4 v = *(const float4*)&Wo[(size_t)(kt * 64 + ki) * 1024 + nt * 64 + f4 * 4];
            f16x4 o = { (_Float16)v.x, (_Float16)v.y, (_Float16)v.z, (_Float16)v.w };
            *(f16x4*)((char*)Th + swzb(ki, f4 * 8)) = o;
        }
        __syncthreads();
        #pragma unroll
        for (int rr = 0; rr < 2; ++rr) {
            int u = rr * 256 + tid;
            int nl = u >> 3, k8 = u & 7;
            f16x8 o;
            #pragma unroll
            for (int j = 0; j < 8; ++j) {
                int ki = k8 * 8 + j;
                o[j] = *(_Float16*)((char*)Th + swzb(ki, nl * 2));
            }
            *(f16x8*)&WoT[(size_t)(nt * 64 + nl) * 1024 + kt * 64 + k8 * 8] = o;
        }
    }
}

// ---------------------------------------------------------------------------
// Q,K projection GEMM (double-f16, 3-term MFMA). m97 structure:
// 128x128 tile, BK=32, linear LDS, global_load_lds(16B), 2-barrier loop.
// grid 512 = 32 mt x 16 nt; nt<8 -> Q tile, nt>=8 -> K tile (homogeneous).
// ---------------------------------------------------------------------------
__global__ __launch_bounds__(256) void gemm_qk(
    const _Float16* __restrict__ AH, const _Float16* __restrict__ AL,
    const _Float16* __restrict__ BTh, const _Float16* __restrict__ BTl,
    _Float16* __restrict__ QbH, _Float16* __restrict__ QbL,
    _Float16* __restrict__ kkTH, _Float16* __restrict__ kkTL) {
    __shared__ _Float16 AsH[128 * 32], AsL[128 * 32];
    __shared__ _Float16 BsH[128 * 32], BsL[128 * 32];
    int wg = ((int)blockIdx.x & 7) * 64 + ((int)blockIdx.x >> 3);
    int mt = wg >> 4, nt = wg & 15;
    int r0 = mt * 128, c0 = nt * 128;
    int tid = threadIdx.x, lane = tid & 63, w = tid >> 6;
    int wr = w >> 1, wc = w & 1;
    int l15 = lane & 15, l4 = lane >> 4;

    f32x4 zero = {0.f, 0.f, 0.f, 0.f};
    f32x4 acc[4][4];
    #pragma unroll
    for (int i = 0; i < 4; ++i)
        #pragma unroll
        for (int j = 0; j < 4; ++j) acc[i][j] = zero;

    for (int kt = 0; kt < 32; ++kt) {
        __syncthreads();
        #pragma unroll
        for (int rr = 0; rr < 2; ++rr) {
            int u = rr * 256 + tid;
            int row = u >> 2, c8 = u & 3;
            size_t ga = (size_t)(r0 + row) * 1024 + kt * 32 + c8 * 8;
            size_t gb = (size_t)(c0 + row) * 1024 + kt * 32 + c8 * 8;
            __builtin_amdgcn_global_load_lds(&AH[ga],  &AsH[u * 8], 16, 0, 0);
            __builtin_amdgcn_global_load_lds(&AL[ga],  &AsL[u * 8], 16, 0, 0);
            __builtin_amdgcn_global_load_lds(&BTh[gb], &BsH[u * 8], 16, 0, 0);
            __builtin_amdgcn_global_load_lds(&BTl[gb], &BsL[u * 8], 16, 0, 0);
        }
        __syncthreads();   // vmcnt(0) drain before barrier (m97 semantics)

        int kb = l4 * 16;
        f16x8 afH[4], afL[4], bfH[4], bfL[4];
        #pragma unroll
        for (int f = 0; f < 4; ++f) {
            int ar = wr * 64 + f * 16 + l15;
            int br = wc * 64 + f * 16 + l15;
            afH[f] = *(const f16x8*)((char*)AsH + ar * 64 + kb);
            afL[f] = *(const f16x8*)((char*)AsL + ar * 64 + kb);
            bfH[f] = *(const f16x8*)((char*)BsH + br * 64 + kb);
            bfL[f] = *(const f16x8*)((char*)BsL + br * 64 + kb);
        }
        #pragma unroll
        for (int i = 0; i < 4; ++i)
            #pragma unroll
            for (int j = 0; j < 4; ++j) {
                acc[i][j] = __builtin_amdgcn_mfma_f32_16x16x32_f16(
                    afH[i], bfH[j], acc[i][j], 0, 0, 0);
                acc[i][j] = __builtin_amdgcn_mfma_f32_16x16x32_f16(
                    afH[i], bfL[j], acc[i][j], 0, 0, 0);
                acc[i][j] = __builtin_amdgcn_mfma_f32_16x16x32_f16(
                    afL[i], bfH[j], acc[i][j], 0, 0, 0);
            }
    }

    #pragma unroll
    for (int i = 0; i < 4; ++i) {
        int grow0 = r0 + wr * 64 + i * 16 + l4 * 4;
        #pragma unroll
        for (int j = 0; j < 4; ++j) {
            int gcol = c0 + wc * 64 + j * 16 + l15;
            if (gcol < 1024) {                       // ---- Q (split) ----
                int hh = gcol >> 6, dk = gcol & 63;
                #pragma unroll
                for (int r = 0; r < 4; ++r) {
                    int grow = grow0 + r;
                    int bb = grow >> 10, s = grow & 1023;
                    float v = acc[i][j][r];
                    _Float16 h = (_Float16)v;
                    size_t idx = (((size_t)hh * 4 + bb) * 1024 + s) * 64 + dk;
                    QbH[idx] = h;
                    QbL[idx] = (_Float16)(v - (float)h);
                }
            } else {                                 // ---- K (split, reshaped) ----
                int hh = (gcol >> 6) & 15, dk = gcol & 63;
                #pragma unroll
                for (int r = 0; r < 4; ++r) {
                    int grow = grow0 + r;
                    int bb = grow >> 10, s = grow & 1023;
                    float v = acc[i][j][r];
                    _Float16 h = (_Float16)v;
                    size_t idx = (((size_t)hh * 4 + bb) * 64 + (s >> 4)) * 1024
                                 + (s & 15) * 64 + dk;
                    kkTH[idx] = h;
                    kkTL[idx] = (_Float16)(v - (float)h);
                }
            }
        }
    }
}

// ---------------------------------------------------------------------------
// V projection GEMM (single f16). 128x64 tiles, BK=32, gload_lds.
// grid 512 = 32 mt x 16 nt. Epilogue writes V2 [hb][dv][t] (pre-transposed).
// ---------------------------------------------------------------------------
__global__ __launch_bounds__(256) void gemm_v(
    const _Float16* __restrict__ AH, const _Float16* __restrict__ BTh,
    _Float16* __restrict__ V2) {
    __shared__ _Float16 As[128 * 32];
    __shared__ _Float16 Bs[64 * 32];
    int wg = ((int)blockIdx.x & 7) * 64 + ((int)blockIdx.x >> 3);
    int mt = wg >> 4, nt = wg & 15;
    int r0 = mt * 128, c0 = nt * 64;
    int tid = threadIdx.x, lane = tid & 63, w = tid >> 6;
    int wr = w >> 1, wc = w & 1;
    int l15 = lane & 15, l4 = lane >> 4;

    f32x4 zero = {0.f, 0.f, 0.f, 0.f};
    f32x4 acc[4][2];
    #pragma unroll
    for (int i = 0; i < 4; ++i)
        #pragma unroll
        for (int j = 0; j < 2; ++j) acc[i][j] = zero;

    for (int kt = 0; kt < 32; ++kt) {
        __syncthreads();
        #pragma unroll
        for (int rr = 0; rr < 2; ++rr) {
            int u = rr * 256 + tid;
            int row = u >> 2, c8 = u & 3;
            size_t ga = (size_t)(r0 + row) * 1024 + kt * 32 + c8 * 8;
            __builtin_amdgcn_global_load_lds(&AH[ga], &As[u * 8], 16, 0, 0);
        }
        {
            int u = tid;
            int row = u >> 2, c8 = u & 3;
            size_t gb = (size_t)(2048 + c0 + row) * 1024 + kt * 32 + c8 * 8;
            __builtin_amdgcn_global_load_lds(&BTh[gb], &Bs[u * 8], 16, 0, 0);
        }
        __syncthreads();

        int kb = l4 * 16;
        f16x8 af[4], bf[2];
        #pragma unroll
        for (int f = 0; f < 4; ++f) {
            int ar = wr * 64 + f * 16 + l15;
            af[f] = *(const f16x8*)((char*)As + ar * 64 + kb);
        }
        #pragma unroll
        for (int j = 0; j < 2; ++j) {
            int br = wc * 32 + j * 16 + l15;
            bf[j] = *(const f16x8*)((char*)Bs + br * 64 + kb);
        }
        #pragma unroll
        for (int i = 0; i < 4; ++i)
            #pragma unroll
            for (int j = 0; j < 2; ++j)
                acc[i][j] = __builtin_amdgcn_mfma_f32_16x16x32_f16(
                    af[i], bf[j], acc[i][j], 0, 0, 0);
    }

    #pragma unroll
    for (int i = 0; i < 4; ++i) {
        int grow0 = r0 + wr * 64 + i * 16 + l4 * 4;
        int bb = grow0 >> 10, s = grow0 & 1023;
        #pragma unroll
        for (int j = 0; j < 2; ++j) {
            int gcol = c0 + wc * 32 + j * 16 + l15;
            int hh = gcol >> 6, dv = gcol & 63;
            f16x4 o = { (_Float16)acc[i][j][0], (_Float16)acc[i][j][1],
                        (_Float16)acc[i][j][2], (_Float16)acc[i][j][3] };
            *(f16x4*)&V2[(((size_t)hh * 4 + bb) * 64 + dv) * 1024 + s] = o;
        }
    }
}

// ---------------------------------------------------------------------------
// kkT [hb][64 d][1024 t] -> K2 [hb][1024 t][64 d], modes: 0=hi, 1=lo.
// ---------------------------------------------------------------------------
__global__ __launch_bounds__(256) void trans_k(const _Float16* __restrict__ kkTH,
                                               const _Float16* __restrict__ kkTL,
                                               _Float16* __restrict__ K2H,
                                               _Float16* __restrict__ K2L) {
    int tt = blockIdx.x;
    size_t hb = blockIdx.y;
    int mode = blockIdx.z;
    const _Float16* src = mode ? kkTL : kkTH;
    _Float16* dst = mode ? K2L : K2H;
    __shared__ _Float16 T[64 * 64];
    int tid = threadIdx.x;
    #pragma unroll
    for (int rr = 0; rr < 2; ++rr) {
        int u = rr * 256 + tid;
        int d = u >> 3, c8 = u & 7;
        f16x8 v = *(const f16x8*)&src[(hb * 64 + d) * 1024 + tt * 64 + c8 * 8];
        *(f16x8*)((char*)T + swzb(d, c8 * 16)) = v;
    }
    __syncthreads();
    #pragma unroll
    for (int rr = 0; rr < 2; ++rr) {
        int u = rr * 256 + tid;
        int ti = u >> 3, d8 = u & 7;
        f16x8 o;
        #pragma unroll
        for (int j = 0; j < 8; ++j)
            o[j] = *(_Float16*)((char*)T + swzb(d8 * 8 + j, ti * 2));
        *(f16x8*)&dst[(hb * 1024 + tt * 64 + ti) * 64 + d8 * 8] = o;
    }
}

// ---------------------------------------------------------------------------
// Flash attention, double-f16 QK^T (3 terms). T14 async staging, LPT order,
// setprio around MFMA clusters. Output -> scrambled concat CC, f16.
// ---------------------------------------------------------------------------
__global__ __launch_bounds__(256) void attn(
    const _Float16* __restrict__ QbH, const _Float16* __restrict__ QbL,
    const _Float16* __restrict__ K2H, const _Float16* __restrict__ K2L,
    const _Float16* __restrict__ V2, _Float16* __restrict__ CC) {
    int qt = 15 - (int)blockIdx.x;       // LPT: long blocks dispatch first
    int b = blockIdx.y, h = blockIdx.z;
    size_t hb = (size_t)h * 4 + b;
    __shared__ _Float16 QsH[64 * 64], QsL[64 * 64];
    __shared__ _Float16 KsH[64 * 64], KsL[64 * 64];
    __shared__ _Float16 Vs[64 * 64], Ps[64 * 64];
    int tid = threadIdx.x, lane = tid & 63, w = tid >> 6;
    int l15 = lane & 15, l4 = lane >> 4;
    int s0 = qt * 64;

    // stage Q (reg -> swizzled LDS)
    #pragma unroll
    for (int rr = 0; rr < 2; ++rr) {
        int u = rr * 256 + tid, row = u >> 3, c8 = u & 7;
        size_t gi = (hb * 1024 + s0 + row) * 64 + c8 * 8;
        int off = swzb(row, c8 * 16);
        *(f16x8*)((char*)QsH + off) = *(const f16x8*)&QbH[gi];
        *(f16x8*)((char*)QsL + off) = *(const f16x8*)&QbL[gi];
    }
    // prologue: load tile 0 into regs
    f16x8 rkH[2], rkL[2], rv[2];
    #pragma unroll
    for (int rr = 0; rr < 2; ++rr) {
        int u = rr * 256 + tid, row = u >> 3, c8 = u & 7;
        size_t ki = (hb * 1024 + row) * 64 + c8 * 8;
        rkH[rr] = *(const f16x8*)&K2H[ki];
        rkL[rr] = *(const f16x8*)&K2L[ki];
        rv[rr]  = *(const f16x8*)&V2[(hb * 64 + row) * 1024 + c8 * 8];
    }
    __syncthreads();
    int srow = w * 16 + l15;
    f16x8 qfH[2], qfL[2];
    #pragma unroll
    for (int ks = 0; ks < 2; ++ks) {
        int kb = (ks * 32 + l4 * 8) * 2;
        qfH[ks] = *(const f16x8*)((char*)QsH + swzb(srow, kb));
        qfL[ks] = *(const f16x8*)((char*)QsL + swzb(srow, kb));
    }

    float m = -__builtin_inff(), lsum = 0.f;
    f32x4 zero = {0.f, 0.f, 0.f, 0.f};
    f32x4 acc2[4] = {zero, zero, zero, zero};
    int sg = s0 + srow;
    int ntile = qt + 1;

    for (int tt = 0; tt < ntile; ++tt) {
        int t0 = tt * 64;
        __syncthreads();                 // prev tile's LDS reads done
        #pragma unroll
        for (int rr = 0; rr < 2; ++rr) { // write current tile from regs
            int u = rr * 256 + tid, row = u >> 3, c8 = u & 7;
            int off = swzb(row, c8 * 16);
            *(f16x8*)((char*)KsH + off) = rkH[rr];
            *(f16x8*)((char*)KsL + off) = rkL[rr];
            *(f16x8*)((char*)Vs + off)  = rv[rr];
        }
        if (tt + 1 < ntile) {            // issue next-tile loads (in flight
            int t0n = t0 + 64;           // during this tile's compute)
            #pragma unroll
            for (int rr = 0; rr < 2; ++rr) {
                int u = rr * 256 + tid, row = u >> 3, c8 = u & 7;
                size_t ki = (hb * 1024 + t0n + row) * 64 + c8 * 8;
                rkH[rr] = *(const f16x8*)&K2H[ki];
                rkL[rr] = *(const f16x8*)&K2L[ki];
                rv[rr]  = *(const f16x8*)&V2[(hb * 64 + row) * 1024 + t0n + c8 * 8];
            }
        }
        __syncthreads();

        f32x4 z[4] = {zero, zero, zero, zero};
        __builtin_amdgcn_s_setprio(1);
        #pragma unroll
        for (int ks = 0; ks < 2; ++ks) {
            int kb = (ks * 32 + l4 * 8) * 2;
            #pragma unroll
            for (int f = 0; f < 4; ++f) {
                int trow = f * 16 + l15;
                f16x8 akH = *(const f16x8*)((char*)KsH + swzb(trow, kb));
                f16x8 akL = *(const f16x8*)((char*)KsL + swzb(trow, kb));
                z[f] = __builtin_amdgcn_mfma_f32_16x16x32_f16(akH, qfH[ks], z[f], 0, 0, 0);
                z[f] = __builtin_amdgcn_mfma_f32_16x16x32_f16(akH, qfL[ks], z[f], 0, 0, 0);
                z[f] = __builtin_amdgcn_mfma_f32_16x16x32_f16(akL, qfH[ks], z[f], 0, 0, 0);
            }
        }
        __builtin_amdgcn_s_setprio(0);
        // scale + causal mask + lane-local row max
        float mt = -__builtin_inff();
        #pragma unroll
        for (int f = 0; f < 4; ++f)
            #pragma unroll
            for (int r = 0; r < 4; ++r) {
                int tg = t0 + f * 16 + l4 * 4 + r;
                float val = z[f][r] * 0.125f;
                val = (tg > sg) ? -__builtin_inff() : val;
                z[f][r] = val;
                mt = fmaxf(mt, val);
            }
        mt = fmaxf(mt, __shfl_xor(mt, 16));
        mt = fmaxf(mt, __shfl_xor(mt, 32));
        float mn = fmaxf(m, mt);
        float corr = __expf(m - mn);
        float ps = 0.f;
        #pragma unroll
        for (int f = 0; f < 4; ++f)
            #pragma unroll
            for (int r = 0; r < 4; ++r) {
                float p = __expf(z[f][r] - mn);
                z[f][r] = p;
                ps += p;
            }
        ps += __shfl_xor(ps, 16);
        ps += __shfl_xor(ps, 32);
        lsum = lsum * corr + ps;
        m = mn;
        #pragma unroll
        for (int f = 0; f < 4; ++f) acc2[f] *= corr;

        // P^T -> Ps (wave-private rows, no barrier needed)
        #pragma unroll
        for (int f = 0; f < 4; ++f) {
            f16x4 pk = { (_Float16)z[f][0], (_Float16)z[f][1],
                         (_Float16)z[f][2], (_Float16)z[f][3] };
            *(f16x4*)((char*)Ps + swzb(srow, (f * 16 + l4 * 4) * 2)) = pk;
        }
        __builtin_amdgcn_s_setprio(1);
        #pragma unroll
        for (int ks = 0; ks < 2; ++ks) {
            int kb = (ks * 32 + l4 * 8) * 2;
            f16x8 bp = *(const f16x8*)((char*)Ps + swzb(srow, kb));
            #pragma unroll
            for (int f = 0; f < 4; ++f) {
                int dvrow = f * 16 + l15;
                f16x8 av = *(const f16x8*)((char*)Vs + swzb(dvrow, kb));
                acc2[f] = __builtin_amdgcn_mfma_f32_16x16x32_f16(av, bp, acc2[f], 0, 0, 0);
            }
        }
        __builtin_amdgcn_s_setprio(0);
    }

    float inv = 1.f / lsum;
    int sp = s0 + srow;
    int bprow = h >> 2;
    int spp = (h & 3) * 256 + b * 64 + (sp >> 4);
    int cb = (sp & 15) * 64;
    #pragma unroll
    for (int f = 0; f < 4; ++f) {
        int dv = f * 16 + l4 * 4;
        f16x4 o = { (_Float16)(acc2[f][0] * inv), (_Float16)(acc2[f][1] * inv),
                    (_Float16)(acc2[f][2] * inv), (_Float16)(acc2[f][3] * inv) };
        *(f16x4*)&CC[((size_t)bprow * 1024 + spp) * 1024 + cb + dv] = o;
    }
}

// ---------------------------------------------------------------------------
// Output projection: CC[4096][1024] @ WoT[1024][1024]^T -> out f32.
// m97 structure: 128x128 tile, BK=64, gload_lds, linear LDS.
// ---------------------------------------------------------------------------
__global__ __launch_bounds__(256) void gemm_out(
    const _Float16* __restrict__ A, const _Float16* __restrict__ BT,
    float* __restrict__ out) {
    __shared__ _Float16 As[128 * 64];
    __shared__ _Float16 Bs[128 * 64];
    int wg = ((int)blockIdx.x & 7) * 32 + ((int)blockIdx.x >> 3);
    int mt = wg >> 3, nt = wg & 7;
    int r0 = mt * 128, c0 = nt * 128;
    int tid = threadIdx.x, lane = tid & 63, w = tid >> 6;
    int wr = w >> 1, wc = w & 1;
    int l15 = lane & 15, l4 = lane >> 4;

    f32x4 zero = {0.f, 0.f, 0.f, 0.f};
    f32x4 acc[4][4];
    #pragma unroll
    for (int i = 0; i < 4; ++i)
        #pragma unroll
        for (int j = 0; j < 4; ++j) acc[i][j] = zero;

    for (int kt = 0; kt < 16; ++kt) {
        __syncthreads();
        #pragma unroll
        for (int rr = 0; rr < 4; ++rr) {
            int u = rr * 256 + tid;
            int row = u >> 3, c8 = u & 7;
            size_t ga = (size_t)(r0 + row) * 1024 + kt * 64 + c8 * 8;
            size_t gb = (size_t)(c0 + row) * 1024 + kt * 64 + c8 * 8;
            __builtin_amdgcn_global_load_lds(&A[ga],  &As[u * 8], 16, 0, 0);
            __builtin_amdgcn_global_load_lds(&BT[gb], &Bs[u * 8], 16, 0, 0);
        }
        __syncthreads();

        #pragma unroll
        for (int ks = 0; ks < 2; ++ks) {
            int kb = (ks * 32 + l4 * 8) * 2;
            f16x8 af[4], bf[4];
            #pragma unroll
            for (int f = 0; f < 4; ++f) {
                int ar = wr * 64 + f * 16 + l15;
                int br = wc * 64 + f * 16 + l15;
                af[f] = *(const f16x8*)((char*)As + ar * 128 + kb);
                bf[f] = *(const f16x8*)((char*)Bs + br * 128 + kb);
            }
            #pragma unroll
            for (int i = 0; i < 4; ++i)
                #pragma unroll
                for (int j = 0; j < 4; ++j)
                    acc[i][j] = __builtin_amdgcn_mfma_f32_16x16x32_f16(
                        af[i], bf[j], acc[i][j], 0, 0, 0);
        }
    }

    #pragma unroll
    for (int i = 0; i < 4; ++i) {
        int grow0 = r0 + wr * 64 + i * 16 + l4 * 4;
        #pragma unroll
        for (int j = 0; j < 4; ++j) {
            int gcol = c0 + wc * 64 + j * 16 + l15;
            #pragma unroll
            for (int r = 0; r < 4; ++r)
                out[(size_t)(grow0 + r) * 1024 + gcol] = acc[i][j][r];
        }
    }
}

// ---------------------------------------------------------------------------
extern "C" void kernel_launch(void* const* d_in, const int* in_sizes, int n_in,
                              void* d_out, int out_size, void* d_ws, size_t ws_size,
                              hipStream_t stream) {
    const float* emb = (const float*)d_in[0];
    const float* Wq  = (const float*)d_in[1];
    const float* Wk  = (const float*)d_in[2];
    const float* Wv  = (const float*)d_in[3];
    const float* Wo  = (const float*)d_in[4];
    float* out = (float*)d_out;

    // ws: 52 MB with aliasing (lifetimes checked against stream order)
    _Float16* embH = (_Float16*)d_ws;          // 4M f16   [K2H aliases later]
    _Float16* embL = embH + 4194304;           // 4M       [K2L aliases later]
    _Float16* WTh  = embL + 4194304;           // 3M       [CC aliases later]
    _Float16* WTl  = WTh + 3145728;            // 2M
    _Float16* WoT  = WTl + 2097152;            // 1M
    _Float16* QbH  = WoT + 1048576;            // 4M
    _Float16* QbL  = QbH + 4194304;            // 4M
    _Float16* V2   = QbL + 4194304;            // 4M  -> total 26M f16 = 52 MB
    _Float16* K2H  = embH;                     // alias: emb dead after gemm_v
    _Float16* K2L  = embL;
    _Float16* CC   = WTh;                      // alias: WT dead after gemm_v
    // kkT hi/lo parked in d_out (16 MB), dead before gemm_out writes it
    _Float16* kkTH = (_Float16*)d_out;
    _Float16* kkTL = kkTH + 4194304;

    cvt_split_emb<<<2048, 256, 0, stream>>>(emb, embH, embL);
    cvt_weights  <<<dim3(16, 64), 256, 0, stream>>>(Wq, Wk, Wv, Wo, WTh, WTl, WoT);
    gemm_qk      <<<512, 256, 0, stream>>>(embH, embL, WTh, WTl, QbH, QbL, kkTH, kkTL);
    gemm_v       <<<512, 256, 0, stream>>>(embH, WTh, V2);
    trans_k      <<<dim3(16, 64, 2), 256, 0, stream>>>(kkTH, kkTL, K2H, K2L);
    attn         <<<dim3(16, 4, 16), 256, 0, stream>>>(QbH, QbL, K2H, K2L, V2, CC);
    gemm_out     <<<256, 256, 0, stream>>>(CC, WoT, out);
}